// Round 1
// baseline (268.387 us; speedup 1.0000x reference)
//
#include <hip/hip_runtime.h>
#include <stdint.h>

#define BATCH 4096
#define NEXP 8
#define DIM 768
#define BM 128
#define BN 128
#define BK 32
#define MAXROWS (BATCH + NEXP * BM)   /* 5120 */
#define ROWBLKS (MAXROWS / BM)        /* 40 */
#define COLBLKS (DIM / BN)            /* 6 */
#define MATELEMS (DIM * DIM)          /* 589824 */

typedef __attribute__((ext_vector_type(4))) float f32x4;
typedef __attribute__((ext_vector_type(8))) __bf16 bf16x8;
typedef __attribute__((ext_vector_type(8))) unsigned short ushort8v;
typedef __attribute__((ext_vector_type(4))) unsigned short ushort4v;

__device__ __forceinline__ unsigned short f2bf(float f) {
  union { float f; unsigned u; } v; v.f = f;
  unsigned r = v.u + 0x7FFFu + ((v.u >> 16) & 1u);
  return (unsigned short)(r >> 16);
}
__device__ __forceinline__ float bf2f(unsigned short h) {
  union { unsigned u; float f; } v; v.u = ((unsigned)h) << 16;
  return v.f;
}

// ---------------------------------------------------------------- convert pooled f32 -> bf16
__global__ __launch_bounds__(256) void k_cvt(const float* __restrict__ src,
                                             unsigned short* __restrict__ dst, int n4) {
  int i = blockIdx.x * 256 + threadIdx.x;
  if (i >= n4) return;
  float4 v = *(const float4*)(src + (size_t)i * 4);
  ushort4v o = { f2bf(v.x), f2bf(v.y), f2bf(v.z), f2bf(v.w) };
  *(ushort4v*)(dst + (size_t)i * 4) = o;
}

// ---------------------------------------------------------------- transpose 33 weight mats f32[K][N] -> bf16[N][K]
__global__ __launch_bounds__(256) void k_transpose(
    const float* __restrict__ Wtfe, const float* __restrict__ W1,
    const float* __restrict__ W2, const float* __restrict__ G1,
    const float* __restrict__ G2, unsigned short* __restrict__ dst)
{
  __shared__ unsigned short lds[64][72];
  const int m = blockIdx.y;
  const float* src;
  if (m == 0)      src = Wtfe;
  else if (m < 9)  src = W1 + (size_t)(m - 1) * MATELEMS;
  else if (m < 17) src = W2 + (size_t)(m - 9) * MATELEMS;
  else if (m < 25) src = G1 + (size_t)(m - 17) * MATELEMS;
  else             src = G2 + (size_t)(m - 25) * MATELEMS;
  unsigned short* d = dst + (size_t)m * MATELEMS;
  const int r0 = (blockIdx.x / 12) * 64;
  const int c0 = (blockIdx.x % 12) * 64;
  const int t = threadIdx.x;
#pragma unroll
  for (int p = 0; p < 4; ++p) {
    int ri = p * 16 + (t >> 4);
    int ci = (t & 15) * 4;
    float4 v = *(const float4*)(src + (size_t)(r0 + ri) * DIM + c0 + ci);
    lds[ri][ci + 0] = f2bf(v.x);
    lds[ri][ci + 1] = f2bf(v.y);
    lds[ri][ci + 2] = f2bf(v.z);
    lds[ri][ci + 3] = f2bf(v.w);
  }
  __syncthreads();
#pragma unroll
  for (int p = 0; p < 2; ++p) {
    int jj = p * 32 + (t >> 3);
    int ii0 = (t & 7) * 8;
    ushort8v o;
#pragma unroll
    for (int u = 0; u < 8; ++u) o[u] = lds[ii0 + u][jj];
    *(ushort8v*)(d + (size_t)(c0 + jj) * DIM + r0 + ii0) = o;
  }
}

// ---------------------------------------------------------------- sort rows by domain, pad segments to BM
// seg[0..8] = padded segment starts, seg[9..16] = true counts
__global__ __launch_bounds__(256) void k_sort(const int* __restrict__ dom,
                                              int* __restrict__ seg,
                                              int* __restrict__ perm,
                                              float* __restrict__ gl) {
  __shared__ int cnt[8], cur[8], pstart[9];
  const int t = threadIdx.x;
  if (t < 8) { cnt[t] = 0; cur[t] = 0; }
  __syncthreads();
  for (int b = t; b < BATCH; b += 256) atomicAdd(&cnt[dom[b]], 1);
  __syncthreads();
  if (t == 0) {
    int acc = 0;
    for (int e = 0; e < 8; ++e) {
      pstart[e] = acc;
      acc += (cnt[e] + BM - 1) / BM * BM;
    }
    pstart[8] = acc;
    for (int e = 0; e < 9; ++e) seg[e] = pstart[e];
    for (int e = 0; e < 8; ++e) seg[9 + e] = cnt[e];
  }
  __syncthreads();
  for (int i = t; i < MAXROWS; i += 256) { perm[i] = 0; gl[i] = 0.0f; }
  __syncthreads();
  for (int b = t; b < BATCH; b += 256) {
    int e = dom[b];
    int pos = pstart[e] + atomicAdd(&cur[e], 1);
    perm[pos] = b;
  }
}

// ---------------------------------------------------------------- grouped MFMA GEMM
// MODE 0: x  = relu(gather(pooled_bf, perm) @ Wtfe + btfe)          -> Out (bf16)
// MODE 1: h  = relu(x @ W1[e] + b1[e])                              -> Out
// MODE 2: df = h @ W2[e] + b2[e]                                    -> Out
// MODE 3: gl += relu(x @ G1[e] + g1b[e]) . Gg[e, :768]              -> atomicAdd
// MODE 4: gl += relu(df @ G2[e] + g2b[e]) . Gg[e, 768:]             -> atomicAdd
template <int MODE>
__global__ __launch_bounds__(256) void k_gemm(
    const unsigned short* __restrict__ A,
    const unsigned short* __restrict__ Wt,   // transposed weights [N][K], expert-strided except MODE 0
    const float* __restrict__ bias,
    const float* __restrict__ Gg,
    const int* __restrict__ seg,
    const int* __restrict__ perm,
    unsigned short* __restrict__ Out,
    float* __restrict__ gl)
{
  __shared__ __align__(16) unsigned short lA[BM * BK];
  __shared__ __align__(16) unsigned short lB[BN * BK];

  const int i0 = blockIdx.x * BM;
  const int total = seg[8];
  if (i0 >= total) return;
  int e = 0;
#pragma unroll
  for (int q = 1; q < 8; ++q) if (i0 >= seg[q]) e = q;

  const int n0 = blockIdx.y * BN;
  const int t = threadIdx.x;
  const int lane = t & 63;
  const int w = t >> 6;
  const int wr = w >> 1, wc = w & 1;

  const unsigned short* We = Wt + (size_t)(MODE == 0 ? 0 : e) * MATELEMS;

  // staging geometry: sub = w*2+c covers rows [sub*16, sub*16+16), each lane loads 8 elems
  int grow[2];
#pragma unroll
  for (int c = 0; c < 2; ++c) {
    int sub = w * 2 + c;
    int row = sub * 16 + (lane >> 2);
    grow[c] = (MODE == 0) ? perm[i0 + row] : (i0 + row);
  }
  const int colb = (lane & 3) * 8;

  f32x4 acc[4][4];
#pragma unroll
  for (int mi = 0; mi < 4; ++mi)
#pragma unroll
    for (int ni = 0; ni < 4; ++ni) acc[mi][ni] = f32x4{0.f, 0.f, 0.f, 0.f};

  for (int kk = 0; kk < DIM; kk += BK) {
    ushort8v ta[2], tb[2];
#pragma unroll
    for (int c = 0; c < 2; ++c) {
      int sub = w * 2 + c;
      int brow = n0 + sub * 16 + (lane >> 2);
      ta[c] = *(const ushort8v*)(A + (size_t)grow[c] * DIM + kk + colb);
      tb[c] = *(const ushort8v*)(We + (size_t)brow * DIM + kk + colb);
    }
    __syncthreads();  // previous iteration's LDS reads are done
#pragma unroll
    for (int c = 0; c < 2; ++c) {
      int sub = w * 2 + c;
      *(ushort8v*)(lA + sub * 512 + lane * 8) = ta[c];
      *(ushort8v*)(lB + sub * 512 + lane * 8) = tb[c];
    }
    __syncthreads();

    const int fr = lane & 15;
    const int kg = (lane >> 4) * 8;
    bf16x8 af[4], bfr[4];
#pragma unroll
    for (int mi = 0; mi < 4; ++mi) {
      ushort8v raw = *(const ushort8v*)(lA + (wr * 64 + mi * 16 + fr) * BK + kg);
      af[mi] = __builtin_bit_cast(bf16x8, raw);
    }
#pragma unroll
    for (int ni = 0; ni < 4; ++ni) {
      ushort8v raw = *(const ushort8v*)(lB + (wc * 64 + ni * 16 + fr) * BK + kg);
      bfr[ni] = __builtin_bit_cast(bf16x8, raw);
    }
#pragma unroll
    for (int mi = 0; mi < 4; ++mi)
#pragma unroll
      for (int ni = 0; ni < 4; ++ni)
        acc[mi][ni] = __builtin_amdgcn_mfma_f32_16x16x32_bf16(af[mi], bfr[ni], acc[mi][ni], 0, 0, 0);
  }

  const int fr = lane & 15;
  const int rg = (lane >> 4) * 4;

  if constexpr (MODE <= 2) {
#pragma unroll
    for (int mi = 0; mi < 4; ++mi) {
#pragma unroll
      for (int ni = 0; ni < 4; ++ni) {
        int gcol = n0 + wc * 64 + ni * 16 + fr;
        float bv = (MODE == 0) ? bias[gcol] : bias[e * DIM + gcol];
#pragma unroll
        for (int r = 0; r < 4; ++r) {
          int go = i0 + wr * 64 + mi * 16 + rg + r;
          float v = acc[mi][ni][r] + bv;
          if (MODE != 2) v = fmaxf(v, 0.0f);
          Out[(size_t)go * DIM + gcol] = f2bf(v);
        }
      }
    }
  } else {
    float psum[4][4];
#pragma unroll
    for (int mi = 0; mi < 4; ++mi)
#pragma unroll
      for (int r = 0; r < 4; ++r) psum[mi][r] = 0.0f;
#pragma unroll
    for (int mi = 0; mi < 4; ++mi) {
#pragma unroll
      for (int ni = 0; ni < 4; ++ni) {
        int gcol = n0 + wc * 64 + ni * 16 + fr;
        float bv = bias[e * DIM + gcol];
        float gg = Gg[e * 2 * DIM + (MODE == 4 ? DIM : 0) + gcol];
#pragma unroll
        for (int r = 0; r < 4; ++r) {
          float v = fmaxf(acc[mi][ni][r] + bv, 0.0f);
          psum[mi][r] += v * gg;
        }
      }
    }
#pragma unroll
    for (int s = 1; s < 16; s <<= 1)
#pragma unroll
      for (int mi = 0; mi < 4; ++mi)
#pragma unroll
        for (int r = 0; r < 4; ++r)
          psum[mi][r] += __shfl_xor(psum[mi][r], s, 64);
    if ((lane & 15) == 0) {
#pragma unroll
      for (int mi = 0; mi < 4; ++mi)
#pragma unroll
        for (int r = 0; r < 4; ++r)
          atomicAdd(&gl[i0 + wr * 64 + mi * 16 + rg + r], psum[mi][r]);
    }
  }
}

// ---------------------------------------------------------------- final blend: out[perm[i]] = g*df + (1-g)*x
__global__ __launch_bounds__(256) void k_blend(
    const int* __restrict__ seg, const int* __restrict__ perm,
    const float* __restrict__ gl, const float* __restrict__ ggb,
    const unsigned short* __restrict__ xbf, const unsigned short* __restrict__ dfbf,
    float* __restrict__ out)
{
  int idx = blockIdx.x * 256 + threadIdx.x;
  int i = idx / 192;
  int q = idx % 192;
  if (i >= seg[8]) return;
  int e = 0;
#pragma unroll
  for (int p = 1; p < 8; ++p) if (i >= seg[p]) e = p;
  if (i - seg[e] >= seg[9 + e]) return;  // padding row
  int b = perm[i];
  float z = gl[i] + ggb[e];
  float g = 1.0f / (1.0f + __expf(-z));
  ushort4v dv = *(const ushort4v*)(dfbf + (size_t)i * DIM + q * 4);
  ushort4v xv = *(const ushort4v*)(xbf + (size_t)i * DIM + q * 4);
  float4 o;
  o.x = g * bf2f(dv[0]) + (1.0f - g) * bf2f(xv[0]);
  o.y = g * bf2f(dv[1]) + (1.0f - g) * bf2f(xv[1]);
  o.z = g * bf2f(dv[2]) + (1.0f - g) * bf2f(xv[2]);
  o.w = g * bf2f(dv[3]) + (1.0f - g) * bf2f(xv[3]);
  *(float4*)(out + (size_t)b * DIM + q * 4) = o;
}

extern "C" void kernel_launch(void* const* d_in, const int* in_sizes, int n_in,
                              void* d_out, int out_size, void* d_ws, size_t ws_size,
                              hipStream_t stream)
{
  const float* pooled = (const float*)d_in[0];
  const int*   dom    = (const int*)d_in[1];
  const float* Wtfe   = (const float*)d_in[2];
  const float* btfe   = (const float*)d_in[3];
  const float* W1     = (const float*)d_in[4];
  const float* b1     = (const float*)d_in[5];
  const float* W2     = (const float*)d_in[6];
  const float* b2     = (const float*)d_in[7];
  const float* G1     = (const float*)d_in[8];
  const float* g1b    = (const float*)d_in[9];
  const float* G2     = (const float*)d_in[10];
  const float* g2b    = (const float*)d_in[11];
  const float* Gg     = (const float*)d_in[12];
  const float* ggb    = (const float*)d_in[13];
  float* out = (float*)d_out;

  char* w = (char*)d_ws;
  size_t o = 0;
  auto alloc = [&](size_t bytes) { char* p = w + o; o += (bytes + 255) & ~(size_t)255; return p; };
  int*            seg  = (int*)alloc(64 * 4);
  int*            perm = (int*)alloc(MAXROWS * 4);
  float*          gl   = (float*)alloc(MAXROWS * 4);
  unsigned short* pbf  = (unsigned short*)alloc((size_t)BATCH * DIM * 2);
  unsigned short* wt   = (unsigned short*)alloc((size_t)33 * MATELEMS * 2);
  unsigned short* xbf  = (unsigned short*)alloc((size_t)MAXROWS * DIM * 2);
  unsigned short* hbf  = (unsigned short*)alloc((size_t)MAXROWS * DIM * 2);
  unsigned short* dfbf = (unsigned short*)alloc((size_t)MAXROWS * DIM * 2);
  if (o > ws_size) return;  // workspace too small: fail loudly (output stays poisoned)

  k_cvt<<<(BATCH * DIM / 4 + 255) / 256, 256, 0, stream>>>(pooled, pbf, BATCH * DIM / 4);
  k_transpose<<<dim3(144, 33), 256, 0, stream>>>(Wtfe, W1, W2, G1, G2, wt);
  k_sort<<<1, 256, 0, stream>>>(dom, seg, perm, gl);

  dim3 gg(ROWBLKS, COLBLKS);
  k_gemm<0><<<gg, 256, 0, stream>>>(pbf,  wt,                          btfe, nullptr, seg, perm, xbf,  nullptr);
  k_gemm<1><<<gg, 256, 0, stream>>>(xbf,  wt + (size_t)1  * MATELEMS,  b1,   nullptr, seg, perm, hbf,  nullptr);
  k_gemm<2><<<gg, 256, 0, stream>>>(hbf,  wt + (size_t)9  * MATELEMS,  b2,   nullptr, seg, perm, dfbf, nullptr);
  k_gemm<3><<<gg, 256, 0, stream>>>(xbf,  wt + (size_t)17 * MATELEMS,  g1b,  Gg,      seg, perm, nullptr, gl);
  k_gemm<4><<<gg, 256, 0, stream>>>(dfbf, wt + (size_t)25 * MATELEMS,  g2b,  Gg,      seg, perm, nullptr, gl);

  k_blend<<<(MAXROWS * 192 + 255) / 256, 256, 0, stream>>>(seg, perm, gl, ggb, xbf, dfbf, out);
}

// Round 8
// 260.683 us; speedup vs baseline: 1.0296x; 1.0296x over previous
//
#include <hip/hip_runtime.h>
#include <stdint.h>

#define BATCH 4096
#define NEXP 8
#define DIM 768
#define BM 64
#define BN 128
#define BK 32
#define MAXROWS (BATCH + NEXP * BM)    /* 4608 */
#define ROWBLKS (MAXROWS / BM)         /* 72 */
#define MATELEMS (DIM * DIM)           /* 589824 */

typedef __attribute__((ext_vector_type(4))) float f32x4;
typedef __attribute__((ext_vector_type(8))) __bf16 bf16x8;
typedef __attribute__((ext_vector_type(8))) unsigned short ushort8v;
typedef __attribute__((ext_vector_type(4))) unsigned short ushort4v;

__device__ __forceinline__ unsigned short f2bf(float f) {
  union { float f; unsigned u; } v; v.f = f;
  unsigned r = v.u + 0x7FFFu + ((v.u >> 16) & 1u);
  return (unsigned short)(r >> 16);
}
__device__ __forceinline__ float bf2f(unsigned short h) {
  union { unsigned u; float f; } v; v.u = ((unsigned)h) << 16;
  return v.f;
}

// ---------------------------------------------------------------- transpose 33 weight mats f32[K][N] -> bf16[N][K]
__global__ __launch_bounds__(256) void k_transpose(
    const float* __restrict__ Wtfe, const float* __restrict__ W1,
    const float* __restrict__ W2, const float* __restrict__ G1,
    const float* __restrict__ G2, unsigned short* __restrict__ dst)
{
  __shared__ unsigned short lds[64][72];
  const int m = blockIdx.y;
  const float* src;
  if (m == 0)      src = Wtfe;
  else if (m < 9)  src = W1 + (size_t)(m - 1) * MATELEMS;
  else if (m < 17) src = W2 + (size_t)(m - 9) * MATELEMS;
  else if (m < 25) src = G1 + (size_t)(m - 17) * MATELEMS;
  else             src = G2 + (size_t)(m - 25) * MATELEMS;
  unsigned short* d = dst + (size_t)m * MATELEMS;
  const int r0 = (blockIdx.x / 12) * 64;
  const int c0 = (blockIdx.x % 12) * 64;
  const int t = threadIdx.x;
#pragma unroll
  for (int p = 0; p < 4; ++p) {
    int ri = p * 16 + (t >> 4);
    int ci = (t & 15) * 4;
    float4 v = *(const float4*)(src + (size_t)(r0 + ri) * DIM + c0 + ci);
    lds[ri][ci + 0] = f2bf(v.x);
    lds[ri][ci + 1] = f2bf(v.y);
    lds[ri][ci + 2] = f2bf(v.z);
    lds[ri][ci + 3] = f2bf(v.w);
  }
  __syncthreads();
#pragma unroll
  for (int p = 0; p < 2; ++p) {
    int jj = p * 32 + (t >> 3);
    int ii0 = (t & 7) * 8;
    ushort8v o;
#pragma unroll
    for (int u = 0; u < 8; ++u) o[u] = lds[ii0 + u][jj];
    *(ushort8v*)(d + (size_t)(c0 + jj) * DIM + r0 + ii0) = o;
  }
}

// ---------------------------------------------------------------- sort rows by domain, pad segments to BM
// (round-0 verified version) seg[0..8] = padded starts, seg[9..16] = true counts
__global__ __launch_bounds__(256) void k_sort(const int* __restrict__ dom,
                                              int* __restrict__ seg,
                                              int* __restrict__ perm,
                                              float* __restrict__ gl) {
  __shared__ int cnt[8], cur[8], pstart[9];
  const int t = threadIdx.x;
  if (t < 8) { cnt[t] = 0; cur[t] = 0; }
  __syncthreads();
  for (int b = t; b < BATCH; b += 256) atomicAdd(&cnt[dom[b]], 1);
  __syncthreads();
  if (t == 0) {
    int acc = 0;
    for (int e = 0; e < 8; ++e) {
      pstart[e] = acc;
      acc += (cnt[e] + BM - 1) / BM * BM;
    }
    pstart[8] = acc;
    for (int e = 0; e < 9; ++e) seg[e] = pstart[e];
    for (int e = 0; e < 8; ++e) seg[9 + e] = cnt[e];
  }
  __syncthreads();
  for (int i = t; i < MAXROWS; i += 256) { perm[i] = 0; gl[i] = 0.0f; }
  __syncthreads();
  for (int b = t; b < BATCH; b += 256) {
    int e = dom[b];
    int pos = pstart[e] + atomicAdd(&cur[e], 1);
    perm[pos] = b;
  }
}

// ---------------------------------------------------------------- grouped MFMA GEMM, 64x128 tile
// round-0 verified core (reg-staged, linear LDS, single buffer, 2 barriers/K-step)
// MODE 0: x  = relu(gather_f32(pooled, perm) @ Wtfe + btfe)   -> Out (bf16)
// MODE 1: y<6 : h = relu(x @ W1[e] + b1[e])                   -> Out
//         y>=6: gl += relu(x @ G1[e] + g1b[e]) . Gg[e,:768]
// MODE 2: df = h @ W2[e] + b2[e]                              -> Out
// MODE 3: gl += relu(df @ G2[e] + g2b[e]) . Gg[e,768:]
template <int MODE>
__global__ __launch_bounds__(256) void k_gemm(
    const void* __restrict__ Ain,
    const unsigned short* __restrict__ Wa,
    const float* __restrict__ ba,
    const unsigned short* __restrict__ Wb,
    const float* __restrict__ bb,
    const float* __restrict__ Gg,
    const int* __restrict__ seg,
    const int* __restrict__ perm,
    unsigned short* __restrict__ Out,
    float* __restrict__ gl)
{
  __shared__ __align__(16) unsigned short lA[BM * BK];   // 4 KB
  __shared__ __align__(16) unsigned short lB[BN * BK];   // 8 KB

  const int i0 = blockIdx.x * BM;
  if (i0 >= seg[8]) return;
  int e = 0;
#pragma unroll
  for (int q = 1; q < 8; ++q) if (i0 >= seg[q]) e = q;

  const bool isgate = (MODE == 3) || (MODE == 1 && blockIdx.y >= 6);
  const int n0 = (MODE == 1 ? (int)(blockIdx.y % 6) : (int)blockIdx.y) * BN;

  const unsigned short* We;
  const float* bias;
  if (MODE == 0) { We = Wa; bias = ba; }
  else if (MODE == 1) {
    We = (isgate ? Wb : Wa) + (size_t)e * MATELEMS;
    bias = (isgate ? bb : ba) + e * DIM;
  } else {
    We = Wa + (size_t)e * MATELEMS;
    bias = ba + e * DIM;
  }

  const int t = threadIdx.x;
  const int lane = t & 63;
  const int w = t >> 6;
  const int wr = w >> 1, wc = w & 1;
  const int srow = lane >> 2;
  const int colb = (lane & 3) * 8;              // element offset within K-tile (linear, no swizzle)

  const int arow_l = w * 16 + srow;             // A row this lane stages (0..63)
  const int garow = (MODE == 0) ? perm[i0 + arow_l] : (i0 + arow_l);

  const unsigned short* Abf = (const unsigned short*)Ain;
  const float* Af32 = (const float*)Ain;

  const int fr = lane & 15;
  const int sl = lane >> 4;
  const int kg = sl * 8;

  f32x4 acc[2][4];
#pragma unroll
  for (int mi = 0; mi < 2; ++mi)
#pragma unroll
    for (int ni = 0; ni < 4; ++ni) acc[mi][ni] = f32x4{0.f, 0.f, 0.f, 0.f};

  for (int kk = 0; kk < DIM; kk += BK) {
    ushort8v ta, tb[2];
    if (MODE == 0) {
      float4 va0 = *(const float4*)(Af32 + (size_t)garow * DIM + kk + colb);
      float4 va1 = *(const float4*)(Af32 + (size_t)garow * DIM + kk + colb + 4);
      ta = ushort8v{ f2bf(va0.x), f2bf(va0.y), f2bf(va0.z), f2bf(va0.w),
                     f2bf(va1.x), f2bf(va1.y), f2bf(va1.z), f2bf(va1.w) };
    } else {
      ta = *(const ushort8v*)(Abf + (size_t)garow * DIM + kk + colb);
    }
#pragma unroll
    for (int c = 0; c < 2; ++c) {
      int brow = n0 + (w * 2 + c) * 16 + srow;
      tb[c] = *(const ushort8v*)(We + (size_t)brow * DIM + kk + colb);
    }
    __syncthreads();  // previous iteration's LDS reads are done
    *(ushort8v*)(lA + arow_l * 32 + colb) = ta;
#pragma unroll
    for (int c = 0; c < 2; ++c)
      *(ushort8v*)(lB + ((w * 2 + c) * 16 + srow) * 32 + colb) = tb[c];
    __syncthreads();

    bf16x8 af[2], bfv[4];
#pragma unroll
    for (int mi = 0; mi < 2; ++mi) {
      ushort8v raw = *(const ushort8v*)(lA + (wr * 32 + mi * 16 + fr) * 32 + kg);
      af[mi] = __builtin_bit_cast(bf16x8, raw);
    }
#pragma unroll
    for (int ni = 0; ni < 4; ++ni) {
      ushort8v raw = *(const ushort8v*)(lB + (wc * 64 + ni * 16 + fr) * 32 + kg);
      bfv[ni] = __builtin_bit_cast(bf16x8, raw);
    }
#pragma unroll
    for (int mi = 0; mi < 2; ++mi)
#pragma unroll
      for (int ni = 0; ni < 4; ++ni)
        acc[mi][ni] = __builtin_amdgcn_mfma_f32_16x16x32_bf16(af[mi], bfv[ni], acc[mi][ni], 0, 0, 0);
  }

  const int rg = sl * 4;
  if (!isgate) {
#pragma unroll
    for (int mi = 0; mi < 2; ++mi) {
#pragma unroll
      for (int ni = 0; ni < 4; ++ni) {
        int gcol = n0 + wc * 64 + ni * 16 + fr;
        float bv = bias[gcol];
#pragma unroll
        for (int r = 0; r < 4; ++r) {
          int go = i0 + wr * 32 + mi * 16 + rg + r;
          float v = acc[mi][ni][r] + bv;
          if (MODE != 2) v = fmaxf(v, 0.0f);
          Out[(size_t)go * DIM + gcol] = f2bf(v);
        }
      }
    }
  } else {
    const int goff = (MODE == 3) ? DIM : 0;
    float psum[2][4];
#pragma unroll
    for (int mi = 0; mi < 2; ++mi)
#pragma unroll
      for (int r = 0; r < 4; ++r) psum[mi][r] = 0.0f;
#pragma unroll
    for (int mi = 0; mi < 2; ++mi) {
#pragma unroll
      for (int ni = 0; ni < 4; ++ni) {
        int gcol = n0 + wc * 64 + ni * 16 + fr;
        float bv = bias[gcol];
        float gg = Gg[e * 2 * DIM + goff + gcol];
#pragma unroll
        for (int r = 0; r < 4; ++r)
          psum[mi][r] += fmaxf(acc[mi][ni][r] + bv, 0.0f) * gg;
      }
    }
#pragma unroll
    for (int s = 1; s < 16; s <<= 1)
#pragma unroll
      for (int mi = 0; mi < 2; ++mi)
#pragma unroll
        for (int r = 0; r < 4; ++r)
          psum[mi][r] += __shfl_xor(psum[mi][r], s, 64);
    if (fr == 0) {
#pragma unroll
      for (int mi = 0; mi < 2; ++mi)
#pragma unroll
        for (int r = 0; r < 4; ++r)
          atomicAdd(&gl[i0 + wr * 32 + mi * 16 + rg + r], psum[mi][r]);
    }
  }
}

// ---------------------------------------------------------------- final blend: out[perm[i]] = g*df + (1-g)*x
__global__ __launch_bounds__(256) void k_blend(
    const int* __restrict__ seg, const int* __restrict__ perm,
    const float* __restrict__ gl, const float* __restrict__ ggb,
    const unsigned short* __restrict__ xbf, const unsigned short* __restrict__ dfbf,
    float* __restrict__ out)
{
  int idx = blockIdx.x * 256 + threadIdx.x;
  int i = idx / 192;
  int q = idx % 192;
  if (i >= seg[8]) return;
  int e = 0;
#pragma unroll
  for (int p = 1; p < 8; ++p) if (i >= seg[p]) e = p;
  if (i - seg[e] >= seg[9 + e]) return;  // padding row
  int b = perm[i];
  float z = gl[i] + ggb[e];
  float g = 1.0f / (1.0f + __expf(-z));
  ushort4v dv = *(const ushort4v*)(dfbf + (size_t)i * DIM + q * 4);
  ushort4v xv = *(const ushort4v*)(xbf + (size_t)i * DIM + q * 4);
  float4 o;
  o.x = g * bf2f(dv[0]) + (1.0f - g) * bf2f(xv[0]);
  o.y = g * bf2f(dv[1]) + (1.0f - g) * bf2f(xv[1]);
  o.z = g * bf2f(dv[2]) + (1.0f - g) * bf2f(xv[2]);
  o.w = g * bf2f(dv[3]) + (1.0f - g) * bf2f(xv[3]);
  *(float4*)(out + (size_t)b * DIM + q * 4) = o;
}

extern "C" void kernel_launch(void* const* d_in, const int* in_sizes, int n_in,
                              void* d_out, int out_size, void* d_ws, size_t ws_size,
                              hipStream_t stream)
{
  const float* pooled = (const float*)d_in[0];
  const int*   dom    = (const int*)d_in[1];
  const float* Wtfe   = (const float*)d_in[2];
  const float* btfe   = (const float*)d_in[3];
  const float* W1     = (const float*)d_in[4];
  const float* b1     = (const float*)d_in[5];
  const float* W2     = (const float*)d_in[6];
  const float* b2     = (const float*)d_in[7];
  const float* G1     = (const float*)d_in[8];
  const float* g1b    = (const float*)d_in[9];
  const float* G2     = (const float*)d_in[10];
  const float* g2b    = (const float*)d_in[11];
  const float* Gg     = (const float*)d_in[12];
  const float* ggb    = (const float*)d_in[13];
  float* out = (float*)d_out;

  char* w = (char*)d_ws;
  size_t o = 0;
  auto alloc = [&](size_t bytes) { char* p = w + o; o += (bytes + 255) & ~(size_t)255; return p; };
  int*            seg  = (int*)alloc(64 * 4);
  int*            perm = (int*)alloc(MAXROWS * 4);
  float*          gl   = (float*)alloc(MAXROWS * 4);
  unsigned short* wt   = (unsigned short*)alloc((size_t)33 * MATELEMS * 2);
  unsigned short* xbf  = (unsigned short*)alloc((size_t)MAXROWS * DIM * 2);
  unsigned short* hbf  = (unsigned short*)alloc((size_t)MAXROWS * DIM * 2);
  unsigned short* dfbf = (unsigned short*)alloc((size_t)MAXROWS * DIM * 2);
  if (o > ws_size) return;  // fail loudly (output stays poisoned)

  k_transpose<<<dim3(144, 33), 256, 0, stream>>>(Wtfe, W1, W2, G1, G2, wt);
  k_sort<<<1, 256, 0, stream>>>(dom, seg, perm, gl);

  const unsigned short* wt0  = wt;
  const unsigned short* wt1  = wt + (size_t)1  * MATELEMS;
  const unsigned short* wt2  = wt + (size_t)9  * MATELEMS;
  const unsigned short* wtg1 = wt + (size_t)17 * MATELEMS;
  const unsigned short* wtg2 = wt + (size_t)25 * MATELEMS;

  k_gemm<0><<<dim3(ROWBLKS, 6),  256, 0, stream>>>(pooled, wt0,  btfe, nullptr, nullptr, Gg, seg, perm, xbf,  gl);
  k_gemm<1><<<dim3(ROWBLKS, 12), 256, 0, stream>>>(xbf,    wt1,  b1,   wtg1,    g1b,     Gg, seg, perm, hbf,  gl);
  k_gemm<2><<<dim3(ROWBLKS, 6),  256, 0, stream>>>(hbf,    wt2,  b2,   nullptr, nullptr, Gg, seg, perm, dfbf, gl);
  k_gemm<3><<<dim3(ROWBLKS, 6),  256, 0, stream>>>(dfbf,   wtg2, g2b,  nullptr, nullptr, Gg, seg, perm, nullptr, gl);

  k_blend<<<(MAXROWS * 192 + 255) / 256, 256, 0, stream>>>(seg, perm, gl, ggb, xbf, dfbf, out);
}

// Round 12
// 236.869 us; speedup vs baseline: 1.1331x; 1.1005x over previous
//
#include <hip/hip_runtime.h>
#include <stdint.h>

#define BATCH 4096
#define NEXP 8
#define DIM 768
#define BM 64
#define BN 128
#define BK 32
#define NT (DIM / BK)                  /* 24 K-steps */
#define MAXROWS (BATCH + NEXP * BM)    /* 4608 */
#define ROWBLKS (MAXROWS / BM)         /* 72 */
#define MATELEMS (DIM * DIM)           /* 589824 */

typedef __attribute__((ext_vector_type(4))) float f32x4;
typedef __attribute__((ext_vector_type(8))) __bf16 bf16x8;
typedef __attribute__((ext_vector_type(8))) unsigned short ushort8v;
typedef __attribute__((ext_vector_type(4))) unsigned short ushort4v;

__device__ __forceinline__ unsigned short f2bf(float f) {
  union { float f; unsigned u; } v; v.f = f;
  unsigned r = v.u + 0x7FFFu + ((v.u >> 16) & 1u);
  return (unsigned short)(r >> 16);
}
__device__ __forceinline__ float bf2f(unsigned short h) {
  union { unsigned u; float f; } v; v.u = ((unsigned)h) << 16;
  return v.f;
}

// ---------------------------------------------------------------- transpose 33 weight mats f32[K][N] -> bf16[N][K]
// blockIdx.y == 33: one block does the domain sort (independent work, folded
// into this launch to save a serial ~10us dispatch).
__global__ __launch_bounds__(256) void k_transpose_sort(
    const float* __restrict__ Wtfe, const float* __restrict__ W1,
    const float* __restrict__ W2, const float* __restrict__ G1,
    const float* __restrict__ G2, unsigned short* __restrict__ dst,
    const int* __restrict__ dom, int* __restrict__ seg,
    int* __restrict__ perm, float* __restrict__ gl)
{
  __shared__ unsigned short lds[64][72];
  __shared__ int cnt[8], cur[8], pstart[9];
  const int t = threadIdx.x;
  const int m = blockIdx.y;

  if (m == 33) {                    // ---- sort path (round-0 verified) ----
    if (blockIdx.x != 0) return;
    if (t < 8) { cnt[t] = 0; cur[t] = 0; }
    __syncthreads();
    for (int b = t; b < BATCH; b += 256) atomicAdd(&cnt[dom[b]], 1);
    __syncthreads();
    if (t == 0) {
      int acc = 0;
      for (int e = 0; e < 8; ++e) {
        pstart[e] = acc;
        acc += (cnt[e] + BM - 1) / BM * BM;
      }
      pstart[8] = acc;
      for (int e = 0; e < 9; ++e) seg[e] = pstart[e];
      for (int e = 0; e < 8; ++e) seg[9 + e] = cnt[e];
    }
    __syncthreads();
    for (int i = t; i < MAXROWS; i += 256) { perm[i] = 0; gl[i] = 0.0f; }
    __syncthreads();
    for (int b = t; b < BATCH; b += 256) {
      int e = dom[b];
      int pos = pstart[e] + atomicAdd(&cur[e], 1);
      perm[pos] = b;
    }
    return;
  }

  // ---- transpose path ----
  const float* src;
  if (m == 0)      src = Wtfe;
  else if (m < 9)  src = W1 + (size_t)(m - 1) * MATELEMS;
  else if (m < 17) src = W2 + (size_t)(m - 9) * MATELEMS;
  else if (m < 25) src = G1 + (size_t)(m - 17) * MATELEMS;
  else             src = G2 + (size_t)(m - 25) * MATELEMS;
  unsigned short* d = dst + (size_t)m * MATELEMS;
  const int r0 = (blockIdx.x / 12) * 64;
  const int c0 = (blockIdx.x % 12) * 64;
#pragma unroll
  for (int p = 0; p < 4; ++p) {
    int ri = p * 16 + (t >> 4);
    int ci = (t & 15) * 4;
    float4 v = *(const float4*)(src + (size_t)(r0 + ri) * DIM + c0 + ci);
    lds[ri][ci + 0] = f2bf(v.x);
    lds[ri][ci + 1] = f2bf(v.y);
    lds[ri][ci + 2] = f2bf(v.z);
    lds[ri][ci + 3] = f2bf(v.w);
  }
  __syncthreads();
#pragma unroll
  for (int p = 0; p < 2; ++p) {
    int jj = p * 32 + (t >> 3);
    int ii0 = (t & 7) * 8;
    ushort8v o;
#pragma unroll
    for (int u = 0; u < 8; ++u) o[u] = lds[ii0 + u][jj];
    *(ushort8v*)(d + (size_t)(c0 + jj) * DIM + r0 + ii0) = o;
  }
}

// ---------------------------------------------------------------- grouped MFMA GEMM, 64x128 tile
// Software-pipelined reg-staged loop (issue loads t+1 before compute t),
// single LDS buffer, 2 barriers/K-step. XCD-aware bijective block swizzle.
// MODE 0: x  = relu(gather_f32(pooled, perm) @ Wtfe + btfe)   -> Out (bf16)
// MODE 1: y<6 : h = relu(x @ W1[e] + b1[e])                   -> Out
//         y>=6: gl += relu(x @ G1[e] + g1b[e]) . Gg[e,:768]
// MODE 2: df = h @ W2[e] + b2[e]                              -> Out
// MODE 3: gl += relu(df @ G2[e] + g2b[e]) . Gg[e,768:]
template <int MODE>
__global__ __launch_bounds__(256) void k_gemm(
    const void* __restrict__ Ain,
    const unsigned short* __restrict__ Wa,
    const float* __restrict__ ba,
    const unsigned short* __restrict__ Wb,
    const float* __restrict__ bb,
    const float* __restrict__ Gg,
    const int* __restrict__ seg,
    const int* __restrict__ perm,
    unsigned short* __restrict__ Out,
    float* __restrict__ gl)
{
  __shared__ __align__(16) unsigned short lA[BM * BK];   // 4 KB
  __shared__ __align__(16) unsigned short lB[BN * BK];   // 8 KB

  // bijective XCD swizzle: grid size (72*6 or 72*12) is divisible by 8,
  // each XCD gets a contiguous chunk of flattened ids -> B panels / A rows
  // stay XCD-local in L2.
  const int nx = gridDim.x;                       // 72
  const int fid = (int)blockIdx.y * nx + (int)blockIdx.x;
  const int chunk = (nx * (int)gridDim.y) >> 3;   // total/8
  const int nid = (fid & 7) * chunk + (fid >> 3);
  const int bx = nid % nx;
  const int by = nid / nx;

  const int i0 = bx * BM;
  if (i0 >= seg[8]) return;
  int e = 0;
#pragma unroll
  for (int q = 1; q < 8; ++q) if (i0 >= seg[q]) e = q;

  const bool isgate = (MODE == 3) || (MODE == 1 && by >= 6);
  const int n0 = (MODE == 1 ? (by % 6) : by) * BN;

  const unsigned short* We;
  const float* bias;
  if (MODE == 0) { We = Wa; bias = ba; }
  else if (MODE == 1) {
    We = (isgate ? Wb : Wa) + (size_t)e * MATELEMS;
    bias = (isgate ? bb : ba) + e * DIM;
  } else {
    We = Wa + (size_t)e * MATELEMS;
    bias = ba + e * DIM;
  }

  const int t = threadIdx.x;
  const int lane = t & 63;
  const int w = t >> 6;
  const int wr = w >> 1, wc = w & 1;
  const int srow = lane >> 2;
  const int colb = (lane & 3) * 8;              // element offset within K-tile (linear, no swizzle)

  const int arow_l = w * 16 + srow;             // A row this lane stages (0..63)
  const int garow = (MODE == 0) ? perm[i0 + arow_l] : (i0 + arow_l);
  const int browl0 = (w * 2 + 0) * 16 + srow;   // B rows this lane stages (0..127)
  const int browl1 = (w * 2 + 1) * 16 + srow;

  const unsigned short* Abf = (const unsigned short*)Ain;
  const float* Af32 = (const float*)Ain;

  const int fr = lane & 15;
  const int sl = lane >> 4;
  const int kg = sl * 8;

  f32x4 acc[2][4];
#pragma unroll
  for (int mi = 0; mi < 2; ++mi)
#pragma unroll
    for (int ni = 0; ni < 4; ++ni) acc[mi][ni] = f32x4{0.f, 0.f, 0.f, 0.f};

  // ---- prologue: load tile 0 into regs
  ushort8v ta, tb0, tb1;
  {
    if (MODE == 0) {
      float4 va0 = *(const float4*)(Af32 + (size_t)garow * DIM + colb);
      float4 va1 = *(const float4*)(Af32 + (size_t)garow * DIM + colb + 4);
      ta = ushort8v{ f2bf(va0.x), f2bf(va0.y), f2bf(va0.z), f2bf(va0.w),
                     f2bf(va1.x), f2bf(va1.y), f2bf(va1.z), f2bf(va1.w) };
    } else {
      ta = *(const ushort8v*)(Abf + (size_t)garow * DIM + colb);
    }
    tb0 = *(const ushort8v*)(We + (size_t)(n0 + browl0) * DIM + colb);
    tb1 = *(const ushort8v*)(We + (size_t)(n0 + browl1) * DIM + colb);
  }

  for (int tt = 0; tt < NT; ++tt) {
    __syncthreads();  // previous iteration's LDS reads done
    *(ushort8v*)(lA + arow_l * 32 + colb) = ta;
    *(ushort8v*)(lB + browl0 * 32 + colb) = tb0;
    *(ushort8v*)(lB + browl1 * 32 + colb) = tb1;
    __syncthreads();

    // issue next tile's global loads; latency hides under this tile's MFMA
    if (tt + 1 < NT) {
      const int kn = (tt + 1) * BK;
      if (MODE == 0) {
        float4 va0 = *(const float4*)(Af32 + (size_t)garow * DIM + kn + colb);
        float4 va1 = *(const float4*)(Af32 + (size_t)garow * DIM + kn + colb + 4);
        ta = ushort8v{ f2bf(va0.x), f2bf(va0.y), f2bf(va0.z), f2bf(va0.w),
                       f2bf(va1.x), f2bf(va1.y), f2bf(va1.z), f2bf(va1.w) };
      } else {
        ta = *(const ushort8v*)(Abf + (size_t)garow * DIM + kn + colb);
      }
      tb0 = *(const ushort8v*)(We + (size_t)(n0 + browl0) * DIM + kn + colb);
      tb1 = *(const ushort8v*)(We + (size_t)(n0 + browl1) * DIM + kn + colb);
    }

    bf16x8 af[2], bfv[4];
#pragma unroll
    for (int mi = 0; mi < 2; ++mi) {
      ushort8v raw = *(const ushort8v*)(lA + (wr * 32 + mi * 16 + fr) * 32 + kg);
      af[mi] = __builtin_bit_cast(bf16x8, raw);
    }
#pragma unroll
    for (int ni = 0; ni < 4; ++ni) {
      ushort8v raw = *(const ushort8v*)(lB + (wc * 64 + ni * 16 + fr) * 32 + kg);
      bfv[ni] = __builtin_bit_cast(bf16x8, raw);
    }
#pragma unroll
    for (int mi = 0; mi < 2; ++mi)
#pragma unroll
      for (int ni = 0; ni < 4; ++ni)
        acc[mi][ni] = __builtin_amdgcn_mfma_f32_16x16x32_bf16(af[mi], bfv[ni], acc[mi][ni], 0, 0, 0);
  }

  const int rg = sl * 4;
  if (!isgate) {
#pragma unroll
    for (int mi = 0; mi < 2; ++mi) {
#pragma unroll
      for (int ni = 0; ni < 4; ++ni) {
        int gcol = n0 + wc * 64 + ni * 16 + fr;
        float bv = bias[gcol];
#pragma unroll
        for (int r = 0; r < 4; ++r) {
          int go = i0 + wr * 32 + mi * 16 + rg + r;
          float v = acc[mi][ni][r] + bv;
          if (MODE != 2) v = fmaxf(v, 0.0f);
          Out[(size_t)go * DIM + gcol] = f2bf(v);
        }
      }
    }
  } else {
    const int goff = (MODE == 3) ? DIM : 0;
    float psum[2][4];
#pragma unroll
    for (int mi = 0; mi < 2; ++mi)
#pragma unroll
      for (int r = 0; r < 4; ++r) psum[mi][r] = 0.0f;
#pragma unroll
    for (int mi = 0; mi < 2; ++mi) {
#pragma unroll
      for (int ni = 0; ni < 4; ++ni) {
        int gcol = n0 + wc * 64 + ni * 16 + fr;
        float bv = bias[gcol];
        float gg = Gg[e * 2 * DIM + goff + gcol];
#pragma unroll
        for (int r = 0; r < 4; ++r)
          psum[mi][r] += fmaxf(acc[mi][ni][r] + bv, 0.0f) * gg;
      }
    }
#pragma unroll
    for (int s = 1; s < 16; s <<= 1)
#pragma unroll
      for (int mi = 0; mi < 2; ++mi)
#pragma unroll
        for (int r = 0; r < 4; ++r)
          psum[mi][r] += __shfl_xor(psum[mi][r], s, 64);
    if (fr == 0) {
#pragma unroll
      for (int mi = 0; mi < 2; ++mi)
#pragma unroll
        for (int r = 0; r < 4; ++r)
          atomicAdd(&gl[i0 + wr * 32 + mi * 16 + rg + r], psum[mi][r]);
    }
  }
}

// ---------------------------------------------------------------- final blend: out[perm[i]] = g*df + (1-g)*x
__global__ __launch_bounds__(256) void k_blend(
    const int* __restrict__ seg, const int* __restrict__ perm,
    const float* __restrict__ gl, const float* __restrict__ ggb,
    const unsigned short* __restrict__ xbf, const unsigned short* __restrict__ dfbf,
    float* __restrict__ out)
{
  int idx = blockIdx.x * 256 + threadIdx.x;
  int i = idx / 192;
  int q = idx % 192;
  if (i >= seg[8]) return;
  int e = 0;
#pragma unroll
  for (int p = 1; p < 8; ++p) if (i >= seg[p]) e = p;
  if (i - seg[e] >= seg[9 + e]) return;  // padding row
  int b = perm[i];
  float z = gl[i] + ggb[e];
  float g = 1.0f / (1.0f + __expf(-z));
  ushort4v dv = *(const ushort4v*)(dfbf + (size_t)i * DIM + q * 4);
  ushort4v xv = *(const ushort4v*)(xbf + (size_t)i * DIM + q * 4);
  float4 o;
  o.x = g * bf2f(dv[0]) + (1.0f - g) * bf2f(xv[0]);
  o.y = g * bf2f(dv[1]) + (1.0f - g) * bf2f(xv[1]);
  o.z = g * bf2f(dv[2]) + (1.0f - g) * bf2f(xv[2]);
  o.w = g * bf2f(dv[3]) + (1.0f - g) * bf2f(xv[3]);
  *(float4*)(out + (size_t)b * DIM + q * 4) = o;
}

extern "C" void kernel_launch(void* const* d_in, const int* in_sizes, int n_in,
                              void* d_out, int out_size, void* d_ws, size_t ws_size,
                              hipStream_t stream)
{
  const float* pooled = (const float*)d_in[0];
  const int*   dom    = (const int*)d_in[1];
  const float* Wtfe   = (const float*)d_in[2];
  const float* btfe   = (const float*)d_in[3];
  const float* W1     = (const float*)d_in[4];
  const float* b1     = (const float*)d_in[5];
  const float* W2     = (const float*)d_in[6];
  const float* b2     = (const float*)d_in[7];
  const float* G1     = (const float*)d_in[8];
  const float* g1b    = (const float*)d_in[9];
  const float* G2     = (const float*)d_in[10];
  const float* g2b    = (const float*)d_in[11];
  const float* Gg     = (const float*)d_in[12];
  const float* ggb    = (const float*)d_in[13];
  float* out = (float*)d_out;

  char* w = (char*)d_ws;
  size_t o = 0;
  auto alloc = [&](size_t bytes) { char* p = w + o; o += (bytes + 255) & ~(size_t)255; return p; };
  int*            seg  = (int*)alloc(64 * 4);
  int*            perm = (int*)alloc(MAXROWS * 4);
  float*          gl   = (float*)alloc(MAXROWS * 4);
  unsigned short* wt   = (unsigned short*)alloc((size_t)33 * MATELEMS * 2);
  unsigned short* xbf  = (unsigned short*)alloc((size_t)MAXROWS * DIM * 2);
  unsigned short* hbf  = (unsigned short*)alloc((size_t)MAXROWS * DIM * 2);
  unsigned short* dfbf = (unsigned short*)alloc((size_t)MAXROWS * DIM * 2);
  if (o > ws_size) return;  // fail loudly (output stays poisoned)

  k_transpose_sort<<<dim3(144, 34), 256, 0, stream>>>(Wtfe, W1, W2, G1, G2, wt,
                                                      dom, seg, perm, gl);

  const unsigned short* wt0  = wt;
  const unsigned short* wt1  = wt + (size_t)1  * MATELEMS;
  const unsigned short* wt2  = wt + (size_t)9  * MATELEMS;
  const unsigned short* wtg1 = wt + (size_t)17 * MATELEMS;
  const unsigned short* wtg2 = wt + (size_t)25 * MATELEMS;

  k_gemm<0><<<dim3(ROWBLKS, 6),  256, 0, stream>>>(pooled, wt0,  btfe, nullptr, nullptr, Gg, seg, perm, xbf,  gl);
  k_gemm<1><<<dim3(ROWBLKS, 12), 256, 0, stream>>>(xbf,    wt1,  b1,   wtg1,    g1b,     Gg, seg, perm, hbf,  gl);
  k_gemm<2><<<dim3(ROWBLKS, 6),  256, 0, stream>>>(hbf,    wt2,  b2,   nullptr, nullptr, Gg, seg, perm, dfbf, gl);
  k_gemm<3><<<dim3(ROWBLKS, 6),  256, 0, stream>>>(dfbf,   wtg2, g2b,  nullptr, nullptr, Gg, seg, perm, nullptr, gl);

  k_blend<<<(MAXROWS * 192 + 255) / 256, 256, 0, stream>>>(seg, perm, gl, ggb, xbf, dfbf, out);
}